// Round 2
// baseline (6033.913 us; speedup 1.0000x reference)
//
#include <hip/hip_runtime.h>
#include <hip/hip_bf16.h>

// FPS: B=64 clouds, M=16384 pts/cloud, K=4096 selections.
// One workgroup per cloud; 1024 threads; 16 points/thread held in VGPRs.
// Per iteration: fused min-update + packed-key argmax, one __syncthreads
// (double-buffered LDS partials), winner coords via uniform L2 load.
// Output dtype: int32 (harness reads d_out as np.int32 for int references).

#define NCLOUDS 64
#define M 16384
#define KSEL 4096
#define NT 1024
#define PPT 16                 // M / NT
#define IDXMASK 0x3FFFu        // 14 bits for local point index
#define KEYMASK 0xFFFFC000u    // top 18 bits of fp32 dist (monotonic for >=0)

static __device__ __forceinline__ unsigned int umax_(unsigned int a, unsigned int b) {
    return a > b ? a : b;
}

__global__ __launch_bounds__(NT, 4)
void fps_kernel(const float* __restrict__ pos, int* __restrict__ out) {
    const int b    = blockIdx.x;
    const int t    = threadIdx.x;
    const int wid  = t >> 6;    // wave id, 0..15
    const int lane = t & 63;

    __shared__ unsigned int skey[2][16];

    const float* __restrict__ cloud = pos + (size_t)b * (M * 3);
    int* __restrict__ outb = out + (size_t)b * KSEL;

    // Load this thread's 16 points into registers (one-time, ~12.6 MB total).
    float px[PPT], py[PPT], pz[PPT], d[PPT];
#pragma unroll
    for (int j = 0; j < PPT; ++j) {
        const int i = j * NT + t;
        px[j] = cloud[i * 3 + 0];
        py[j] = cloud[i * 3 + 1];
        pz[j] = cloud[i * 3 + 2];
    }

    // First selection: local index 0 (reference: random_first=False).
    const float sx = cloud[0], sy = cloud[1], sz = cloud[2];
    if (t == 0) outb[0] = b * M;

    // Init distances + packed argmax keys (4 parallel accumulators for ILP).
    unsigned int key[4] = {0u, 0u, 0u, 0u};
#pragma unroll
    for (int j = 0; j < PPT; ++j) {
        const float dx = px[j] - sx;
        const float dy = py[j] - sy;
        const float dz = pz[j] - sz;
        const float nd = dx * dx + dy * dy + dz * dz;
        d[j] = nd;
        const unsigned int kk =
            (__float_as_uint(nd) & KEYMASK) | (unsigned int)(j * NT + t);
        key[j & 3] = umax_(key[j & 3], kk);
    }

    for (int k = 1; k < KSEL; ++k) {
        // ---- block argmax of current dist (via packed keys) ----
        unsigned int rk = umax_(umax_(key[0], key[1]), umax_(key[2], key[3]));
#pragma unroll
        for (int s = 1; s < 64; s <<= 1)
            rk = umax_(rk, (unsigned int)__shfl_xor((int)rk, s, 64));

        const int buf = k & 1;
        if (lane == 0) skey[buf][wid] = rk;
        __syncthreads();  // the only barrier per iteration (double-buffered)

        // Every wave redundantly reduces the 16 per-wave partials.
        unsigned int g = skey[buf][lane & 15];
#pragma unroll
        for (int s = 1; s < 16; s <<= 1)
            g = umax_(g, (unsigned int)__shfl_xor((int)g, s, 64));

        const int wi = __builtin_amdgcn_readfirstlane((int)(g & IDXMASK));
        if (t == 0) outb[k] = b * M + wi;

        // Winner coords: uniform (scalarized) load, L2-resident.
        const float wx = cloud[wi * 3 + 0];
        const float wy = cloud[wi * 3 + 1];
        const float wz = cloud[wi * 3 + 2];

        // ---- fused min-update + argmax key tracking ----
        key[0] = key[1] = key[2] = key[3] = 0u;
#pragma unroll
        for (int j = 0; j < PPT; ++j) {
            const float dx = px[j] - wx;
            const float dy = py[j] - wy;
            const float dz = pz[j] - wz;
            const float nd = fminf(d[j], dx * dx + dy * dy + dz * dz);
            d[j] = nd;
            const unsigned int kk =
                (__float_as_uint(nd) & KEYMASK) | (unsigned int)(j * NT + t);
            key[j & 3] = umax_(key[j & 3], kk);
        }
    }
}

extern "C" void kernel_launch(void* const* d_in, const int* in_sizes, int n_in,
                              void* d_out, int out_size, void* d_ws, size_t ws_size,
                              hipStream_t stream) {
    const float* pos = (const float*)d_in[0];
    // d_in[1] (batch) is uniform B x M — unused.
    int* out = (int*)d_out;
    fps_kernel<<<dim3(NCLOUDS), dim3(NT), 0, stream>>>(pos, out);
}

// Round 3
// 4892.816 us; speedup vs baseline: 1.2332x; 1.2332x over previous
//
#include <hip/hip_runtime.h>
#include <hip/hip_bf16.h>

// FPS: B=64 clouds, M=16384 pts/cloud, K=4096 selections. int32 output.
// One workgroup per cloud; 1024 threads; 16 points/thread PINNED in VGPRs
// (asm pin defeats compiler rematerialization of the global loads — round-2
// profile showed VGPR_Count=56, i.e. coords were reloaded from L2 every iter).
// Per iteration: e[j] = min(e[j], |s|^2 - 2 p.s)  (e = d - |p|^2, 8 VALU/pt),
// packed-key argmax via DPP row-reduce (no ds_bpermute shuffles), one
// __syncthreads with double-buffered LDS partials, winner coords via uniform
// s_load (L2-resident).

#define NCLOUDS 64
#define M 16384
#define KSEL 4096
#define NT 1024
#define PPT 16                   // M / NT
#define IDXMASK   0x3FFFu        // 14-bit global-in-cloud index
#define TRUNCMASK 0x7FFFC000u    // 17 bits of fp32 dist (sign cleared)
#define JMASK     0x7FFFFFF0u    // 27 bits of fp32 dist | 4-bit j (per-thread)

static __device__ __forceinline__ unsigned int umax_(unsigned int a, unsigned int b) {
    return a > b ? a : b;
}

// One DPP max step: v = max(v, lanes shifted per CTRL); invalid lanes -> 0.
template <int CTRL>
static __device__ __forceinline__ unsigned int dpp_max(unsigned int v) {
    unsigned int s = (unsigned int)__builtin_amdgcn_update_dpp(
        0, (int)v, CTRL, 0xF, 0xF, false);
    return umax_(v, s);
}

// Full 64-lane max; result valid in lane 63. (row_shr 1/2/4/8, bcast15, bcast31)
static __device__ __forceinline__ unsigned int wave_max63(unsigned int v) {
    v = dpp_max<0x111>(v);
    v = dpp_max<0x112>(v);
    v = dpp_max<0x114>(v);
    v = dpp_max<0x118>(v);
    v = dpp_max<0x142>(v);
    v = dpp_max<0x143>(v);
    return v;
}

__global__ __launch_bounds__(NT, 1)
void fps_kernel(const float* __restrict__ pos, int* __restrict__ out) {
    const int b    = blockIdx.x;
    const int t    = threadIdx.x;
    const int wid  = t >> 6;     // 0..15
    const int lane = t & 63;

    __shared__ unsigned int skey[2][16];

    const float* __restrict__ cloud = pos + (size_t)b * (M * 3);
    int* __restrict__ outb = out + (size_t)b * KSEL;

    // ---- prologue: load 16 points/thread, pin them in VGPRs ----
    float px[PPT], py[PPT], pz[PPT], pp[PPT], e[PPT];
#pragma unroll
    for (int j = 0; j < PPT; ++j) {
        const int i = j * NT + t;
        px[j] = cloud[i * 3 + 0];
        py[j] = cloud[i * 3 + 1];
        pz[j] = cloud[i * 3 + 2];
        pp[j] = px[j] * px[j] + py[j] * py[j] + pz[j] * pz[j];
        asm volatile("" : "+v"(px[j]), "+v"(py[j]), "+v"(pz[j]), "+v"(pp[j]));
    }

    // first sample: local index 0 (random_first=False)
    float wx = cloud[0], wy = cloud[1], wz = cloud[2];
    if (t == 0) outb[0] = b * M;
    float sww = wx * wx + wy * wy + wz * wz;

    // init e[j] = d0 - pp = sww - 2*dot ; per-thread key = distbits|j
    unsigned int key[4] = {0u, 0u, 0u, 0u};
#pragma unroll
    for (int j = 0; j < PPT; ++j) {
        float dot = px[j] * wx;
        dot = __builtin_fmaf(py[j], wy, dot);
        dot = __builtin_fmaf(pz[j], wz, dot);
        e[j] = __builtin_fmaf(dot, -2.0f, sww);
        const float dk = e[j] + pp[j];
        const unsigned int kk = (__float_as_uint(dk) & JMASK) | (unsigned int)j;
        key[j & 3] = umax_(key[j & 3], kk);
    }

    for (int k = 1; k < KSEL; ++k) {
        // ---- per-thread key -> block key (17-bit dist | 14-bit idx) ----
        unsigned int tk = umax_(umax_(key[0], key[1]), umax_(key[2], key[3]));
        const unsigned int jj = tk & 15u;
        tk = (tk & TRUNCMASK) | ((unsigned int)t + (jj << 10));

        // ---- wave max via DPP, then one barrier, then 16-partial DPP max ----
        tk = wave_max63(tk);
        const int buf = k & 1;
        if (lane == 63) skey[buf][wid] = tk;
        __syncthreads();

        unsigned int g = skey[buf][lane & 15];
        g = dpp_max<0x111>(g);
        g = dpp_max<0x112>(g);
        g = dpp_max<0x114>(g);
        g = dpp_max<0x118>(g);
        const unsigned int gmax = (unsigned int)__builtin_amdgcn_readlane((int)g, 15);

        const int wi = (int)(gmax & IDXMASK);
        if (t == 0) outb[k] = b * M + wi;

        // winner coords: uniform scalar load, L2-resident
        wx = cloud[wi * 3 + 0];
        wy = cloud[wi * 3 + 1];
        wz = cloud[wi * 3 + 2];
        sww = wx * wx + wy * wy + wz * wz;

        // ---- fused min-update + per-thread argmax (8 VALU/pt) ----
        key[0] = key[1] = key[2] = key[3] = 0u;
#pragma unroll
        for (int j = 0; j < PPT; ++j) {
            float dot = px[j] * wx;
            dot = __builtin_fmaf(py[j], wy, dot);
            dot = __builtin_fmaf(pz[j], wz, dot);
            const float cand = __builtin_fmaf(dot, -2.0f, sww);
            e[j] = fminf(e[j], cand);
            const float dk = e[j] + pp[j];     // >= -eps; sign cleared by JMASK
            const unsigned int kk = (__float_as_uint(dk) & JMASK) | (unsigned int)j;
            key[j & 3] = umax_(key[j & 3], kk);
        }
    }
}

extern "C" void kernel_launch(void* const* d_in, const int* in_sizes, int n_in,
                              void* d_out, int out_size, void* d_ws, size_t ws_size,
                              hipStream_t stream) {
    const float* pos = (const float*)d_in[0];
    // d_in[1] (batch) is uniform B x M — unused.
    int* out = (int*)d_out;
    fps_kernel<<<dim3(NCLOUDS), dim3(NT), 0, stream>>>(pos, out);
}